// Round 6
// baseline (778.026 us; speedup 1.0000x reference)
//
#include <hip/hip_runtime.h>
#include <cstdint>
#include <cstddef>

constexpr int Hd  = 256;
constexpr int N_P = 100000;
constexpr int N_A = 20000;
constexpr int F_P = 512;
constexpr int D_A = 128;

typedef short bf16x8 __attribute__((ext_vector_type(8)));
typedef float f32x4  __attribute__((ext_vector_type(4)));

// fp32 -> bf16 round-to-nearest-even
__device__ __forceinline__ unsigned short f2b(float x) {
    unsigned u = __float_as_uint(x);
    u += 0x7fffu + ((u >> 16) & 1u);
    return (unsigned short)(u >> 16);
}
__device__ __forceinline__ float b2f(unsigned short h) {
    return __uint_as_float((unsigned)h << 16);
}

// split fp32 into bf16 hi + bf16 lo (truncation; combined error ~2^-16 rel)
__device__ __forceinline__ void bsplit(float x, unsigned short& hi, unsigned short& lo) {
    const unsigned u = __float_as_uint(x);
    hi = (unsigned short)(u >> 16);
    const float r = x - __uint_as_float(u & 0xffff0000u);
    lo = (unsigned short)(__float_as_uint(r) >> 16);
}

// ---------------------------------------------------------------------------
// prep: pack 3 MFMA W-pairs (bf16 hi/lo fragment layout), W1rc as bf16
// row-major (for sparse kernel), and 3 bias concats. One launch, 920 blocks.
// ---------------------------------------------------------------------------
__global__ void prep_kernel(const float* __restrict__ W1sa, const float* __restrict__ W1rw,
                            const float* __restrict__ W2sa, const float* __restrict__ W2rw,
                            const float* __restrict__ W2rc, const float* __restrict__ W2sp,
                            const float* __restrict__ W1rc,
                            const float* __restrict__ b1sa, const float* __restrict__ b1rw,
                            const float* __restrict__ b2sa, const float* __restrict__ b2rw,
                            const float* __restrict__ b2rc, const float* __restrict__ b2sp,
                            unsigned short* __restrict__ w1h,  unsigned short* __restrict__ w1l,
                            unsigned short* __restrict__ wA2h, unsigned short* __restrict__ wA2l,
                            unsigned short* __restrict__ wP2h, unsigned short* __restrict__ wP2l,
                            unsigned short* __restrict__ wcb,
                            float* __restrict__ bc1, float* __restrict__ bcA2,
                            float* __restrict__ bcP2) {
    const int b = blockIdx.x;
    if (b < 640) {
        const float *Wa, *Wb; unsigned short *wh, *wl; int rel;
        if (b < 128)      { Wa = W1sa; Wb = W1rw; wh = w1h;  wl = w1l;  rel = b; }
        else if (b < 384) { Wa = W2sa; Wb = W2rw; wh = wA2h; wl = wA2l; rel = b - 128; }
        else              { Wa = W2rc; Wb = W2sp; wh = wP2h; wl = wP2l; rel = b - 384; }
        const int ks  = rel >> 5;
        const int nfg = rel & 31;
        const int l   = threadIdx.x;
        const float* W = (nfg < 16) ? Wa : Wb;
        const int col  = (nfg & 15) * 16 + (l & 15);
        const size_t base = ((size_t)rel * 64 + l) * 8;
        #pragma unroll
        for (int j = 0; j < 8; ++j) {
            const int k = ks * 32 + ((l >> 4) * 8) + j;
            unsigned short h, lw;
            bsplit(W[(size_t)k * Hd + col], h, lw);
            wh[base + j] = h;
            wl[base + j] = lw;
        }
    } else if (b < 896) {
        // W1rc fp32 -> bf16 row-major [512][256]
        const int i0 = (b - 640) * 512 + threadIdx.x * 8;
        #pragma unroll
        for (int j = 0; j < 8; ++j) wcb[i0 + j] = f2b(W1rc[i0 + j]);
    } else {
        const int t     = (b - 896) * 64 + threadIdx.x;   // 0..1535
        const int which = t >> 9;
        const int idx   = t & 511;
        const float* src; float* dst;
        if (which == 0)      { src = (idx < 256) ? b1sa : b1rw; dst = bc1; }
        else if (which == 1) { src = (idx < 256) ? b2sa : b2rw; dst = bcA2; }
        else                 { src = (idx < 256) ? b2rc : b2sp; dst = bcP2; }
        dst[idx] = src[idx & 255];
    }
}

// ---------------------------------------------------------------------------
// Dual-output MFMA GEMM, split-bf16 3-product. Outputs independently fp32 or
// bf16. In-place safe for Ob==A (fp32): A fully staged to LDS before
// __syncthreads(), stores only after.
// ---------------------------------------------------------------------------
__global__ void mfma_dual_kernel(const float* __restrict__ A, const int K,
                                 const unsigned short* __restrict__ whi,
                                 const unsigned short* __restrict__ wlo,
                                 const float* __restrict__ bcat,
                                 void* __restrict__ Oa, void* __restrict__ Ob,
                                 const int actA, const int actB,
                                 const int bfA, const int bfB) {
    extern __shared__ char smem[];
    char* sh = smem;
    char* sl = smem + 32 * K * 2;
    const int  tid = threadIdx.x;
    const int  wid = tid >> 6;
    const int  l   = tid & 63;
    const long m0  = (long)blockIdx.x * 32;
    const int  rowStride = 2 * K;

    const int kq4 = K >> 2;
    for (int i = tid; i < 32 * kq4; i += 256) {
        const int row = i / kq4;
        const int kq  = i - row * kq4;
        const float4 v = *(const float4*)(A + (m0 + row) * K + kq * 4);
        unsigned short h0, h1, h2, h3, l0, l1, l2, l3;
        bsplit(v.x, h0, l0); bsplit(v.y, h1, l1);
        bsplit(v.z, h2, l2); bsplit(v.w, h3, l3);
        int ofs = row * rowStride + ((kq * 8) ^ ((row & 7) << 4));
        *(ushort4*)(sh + ofs) = make_ushort4(h0, h1, h2, h3);
        *(ushort4*)(sl + ofs) = make_ushort4(l0, l1, l2, l3);
    }
    __syncthreads();

    f32x4 acc[2][8];
    #pragma unroll
    for (int nf = 0; nf < 8; ++nf) {
        const float b = bcat[wid * 128 + nf * 16 + (l & 15)];
        acc[0][nf] = (f32x4){b, b, b, b};
        acc[1][nf] = (f32x4){b, b, b, b};
    }

    const int kb  = (l >> 4) * 16;
    const int r0  = l & 15;
    const int r1  = 16 + r0;
    const int sw  = (l & 7) << 4;
    const int ro0 = r0 * rowStride;
    const int ro1 = r1 * rowStride;
    for (int ks = 0; ks < (K >> 5); ++ks) {
        const int bk = (ks * 64 + kb) ^ sw;
        const bf16x8 ah0 = *(const bf16x8*)(sh + ro0 + bk);
        const bf16x8 al0 = *(const bf16x8*)(sl + ro0 + bk);
        const bf16x8 ah1 = *(const bf16x8*)(sh + ro1 + bk);
        const bf16x8 al1 = *(const bf16x8*)(sl + ro1 + bk);
        const size_t wbase = (((size_t)ks * 32 + wid * 8) * 64 + l) * 8;
        #pragma unroll
        for (int nf = 0; nf < 8; ++nf) {
            const bf16x8 bh = *(const bf16x8*)(whi + wbase + (size_t)nf * 512);
            const bf16x8 bl = *(const bf16x8*)(wlo + wbase + (size_t)nf * 512);
            acc[0][nf] = __builtin_amdgcn_mfma_f32_16x16x32_bf16(ah0, bh, acc[0][nf], 0, 0, 0);
            acc[1][nf] = __builtin_amdgcn_mfma_f32_16x16x32_bf16(ah1, bh, acc[1][nf], 0, 0, 0);
            acc[0][nf] = __builtin_amdgcn_mfma_f32_16x16x32_bf16(al0, bh, acc[0][nf], 0, 0, 0);
            acc[1][nf] = __builtin_amdgcn_mfma_f32_16x16x32_bf16(al1, bh, acc[1][nf], 0, 0, 0);
            acc[0][nf] = __builtin_amdgcn_mfma_f32_16x16x32_bf16(ah0, bl, acc[0][nf], 0, 0, 0);
            acc[1][nf] = __builtin_amdgcn_mfma_f32_16x16x32_bf16(ah1, bl, acc[1][nf], 0, 0, 0);
        }
    }

    #pragma unroll
    for (int mf = 0; mf < 2; ++mf) {
        #pragma unroll
        for (int nf = 0; nf < 8; ++nf) {
            const int colg = wid * 128 + nf * 16 + (l & 15);
            void* O;
            int col, act, isbf;
            if (colg < 256) { O = Oa; col = colg;       act = actA; isbf = bfA; }
            else            { O = Ob; col = colg - 256; act = actB; isbf = bfB; }
            const long row = m0 + mf * 16 + ((l >> 4) * 4);
            const f32x4 v = acc[mf][nf];
            #pragma unroll
            for (int r = 0; r < 4; ++r) {
                float x = v[r];
                if (act) x = x > 0.f ? x : expm1f(x);
                if (isbf) ((unsigned short*)O)[(row + r) * Hd + col] = f2b(x);
                else      ((float*)O)[(row + r) * Hd + col] = x;
            }
        }
    }
}

// ---------------------------------------------------------------------------
// Sparse dual GEMM over binary multi-hot pf. Wave = 4 rows. Phase 1: ballot-
// prefix compaction of (k | row<<9 [| pad<<11]) entries into a flat LDS queue
// (grouped by row). Phase 2: chunk-4 A/B ping-pong walk -> 8 wave-loads
// (4x fp32 W-row + 4x bf16 W-row = 6KB) in flight, counted vmcnt waits.
// ---------------------------------------------------------------------------
struct SpChunk {
    float4  s0, s1, s2, s3;
    ushort4 c0, c1, c2, c3;
    float   f0, f1, f2, f3;
    int     r0, r1, r2, r3;
};

__device__ __forceinline__ void sp_issue(const unsigned short* __restrict__ wq, const int chunk,
                                         const float* __restrict__ Ws,
                                         const unsigned short* __restrict__ Wc,
                                         const int lane, SpChunk& C) {
    const ushort4 ee = *(const ushort4*)(wq + chunk * 4);
#define SP_ONE(EV, SS, CC, FF, RR) { \
    const int ent = (int)(EV); const int k = ent & 511; \
    FF = (ent & 2048) ? 0.f : 1.f; \
    RR = (ent >> 9) & 3; \
    SS = ((const float4*)(Ws + (size_t)k * Hd))[lane]; \
    CC = ((const ushort4*)(Wc + (size_t)k * Hd))[lane]; }
    SP_ONE(ee.x, C.s0, C.c0, C.f0, C.r0)
    SP_ONE(ee.y, C.s1, C.c1, C.f1, C.r1)
    SP_ONE(ee.z, C.s2, C.c2, C.f2, C.r2)
    SP_ONE(ee.w, C.s3, C.c3, C.f3, C.r3)
#undef SP_ONE
}

__device__ __forceinline__ void acc1(float4& aS, float4& aC,
                                     const float4 ws, const ushort4 wc, const float f) {
    aS.x = fmaf(f, ws.x, aS.x); aS.y = fmaf(f, ws.y, aS.y);
    aS.z = fmaf(f, ws.z, aS.z); aS.w = fmaf(f, ws.w, aS.w);
    aC.x = fmaf(f, b2f(wc.x), aC.x); aC.y = fmaf(f, b2f(wc.y), aC.y);
    aC.z = fmaf(f, b2f(wc.z), aC.z); aC.w = fmaf(f, b2f(wc.w), aC.w);
}

__device__ __forceinline__ void sp_acc(const SpChunk& C,
        float4& aS0, float4& aC0, float4& aS1, float4& aC1,
        float4& aS2, float4& aC2, float4& aS3, float4& aC3) {
#define SP_A(RR, SS, CC, FF) \
    if (RR == 0)      acc1(aS0, aC0, SS, CC, FF); \
    else if (RR == 1) acc1(aS1, aC1, SS, CC, FF); \
    else if (RR == 2) acc1(aS2, aC2, SS, CC, FF); \
    else              acc1(aS3, aC3, SS, CC, FF);
    SP_A(C.r0, C.s0, C.c0, C.f0)
    SP_A(C.r1, C.s1, C.c1, C.f1)
    SP_A(C.r2, C.s2, C.c2, C.f2)
    SP_A(C.r3, C.s3, C.c3, C.f3)
#undef SP_A
}

__global__ void sparse_dual_kernel(const float* __restrict__ pf,
                                   const float* __restrict__ Ws, const float* __restrict__ bs,
                                   const unsigned short* __restrict__ Wc, const float* __restrict__ bc,
                                   float* __restrict__ outS, unsigned short* __restrict__ outC) {
    __shared__ unsigned short q[4][2048];
    const int lane = threadIdx.x & 63;
    const int wid  = threadIdx.x >> 6;
    const long r0  = (long)blockIdx.x * 16 + wid * 4;
    unsigned short* wq = q[wid];

    // ---- phase 0: load pf for 4 rows (8 dwordx4 in flight) ----
    const float4* p0 = (const float4*)(pf + (r0 + 0) * F_P);
    const float4* p1 = (const float4*)(pf + (r0 + 1) * F_P);
    const float4* p2 = (const float4*)(pf + (r0 + 2) * F_P);
    const float4* p3 = (const float4*)(pf + (r0 + 3) * F_P);
    const float4 A0 = p0[lane], B0 = p0[64 + lane];
    const float4 A1 = p1[lane], B1 = p1[64 + lane];
    const float4 A2 = p2[lane], B2 = p2[64 + lane];
    const float4 A3 = p3[lane], B3 = p3[64 + lane];

    // ---- phase 1: ballot-prefix compaction ----
    int qn = 0;
#define SP_GRP(VAL, KOFS, ROW) { \
    const bool nz = (VAL) != 0.f; \
    const unsigned long long mk = __ballot(nz); \
    if (nz) { \
        const int within = __builtin_amdgcn_mbcnt_hi((unsigned)(mk >> 32), \
                           __builtin_amdgcn_mbcnt_lo((unsigned)mk, 0)); \
        wq[qn + within] = (unsigned short)(((KOFS) + lane * 4) | ((ROW) << 9)); \
    } \
    qn += (int)__popcll(mk); }
    SP_GRP(A0.x, 0,   0) SP_GRP(A0.y, 1,   0) SP_GRP(A0.z, 2,   0) SP_GRP(A0.w, 3,   0)
    SP_GRP(B0.x, 256, 0) SP_GRP(B0.y, 257, 0) SP_GRP(B0.z, 258, 0) SP_GRP(B0.w, 259, 0)
    SP_GRP(A1.x, 0,   1) SP_GRP(A1.y, 1,   1) SP_GRP(A1.z, 2,   1) SP_GRP(A1.w, 3,   1)
    SP_GRP(B1.x, 256, 1) SP_GRP(B1.y, 257, 1) SP_GRP(B1.z, 258, 1) SP_GRP(B1.w, 259, 1)
    SP_GRP(A2.x, 0,   2) SP_GRP(A2.y, 1,   2) SP_GRP(A2.z, 2,   2) SP_GRP(A2.w, 3,   2)
    SP_GRP(B2.x, 256, 2) SP_GRP(B2.y, 257, 2) SP_GRP(B2.z, 258, 2) SP_GRP(B2.w, 259, 2)
    SP_GRP(A3.x, 0,   3) SP_GRP(A3.y, 1,   3) SP_GRP(A3.z, 2,   3) SP_GRP(A3.w, 3,   3)
    SP_GRP(B3.x, 256, 3) SP_GRP(B3.y, 257, 3) SP_GRP(B3.z, 258, 3) SP_GRP(B3.w, 259, 3)
#undef SP_GRP
    const int qnp = (qn + 7) & ~7;
    if (lane < qnp - qn) wq[qn + lane] = 0x0800;   // pad entries (scale 0)

    // ---- phase 2: pipelined walk ----
    float4 aS0 = ((const float4*)bs)[lane];
    float4 aC0 = ((const float4*)bc)[lane];
    float4 aS1 = aS0, aS2 = aS0, aS3 = aS0;
    float4 aC1 = aC0, aC2 = aC0, aC3 = aC0;

    if (qn > 0) {
        const int nc = qnp >> 2;                 // even, >= 2
        SpChunk CA, CB;
        sp_issue(wq, 0, Ws, Wc, lane, CA);
        int c = 1;
        for (; c + 1 < nc; c += 2) {
            sp_issue(wq, c, Ws, Wc, lane, CB);
            sp_acc(CA, aS0, aC0, aS1, aC1, aS2, aC2, aS3, aC3);
            sp_issue(wq, c + 1, Ws, Wc, lane, CA);
            sp_acc(CB, aS0, aC0, aS1, aC1, aS2, aC2, aS3, aC3);
        }
        sp_issue(wq, nc - 1, Ws, Wc, lane, CB);
        sp_acc(CA, aS0, aC0, aS1, aC1, aS2, aC2, aS3, aC3);
        sp_acc(CB, aS0, aC0, aS1, aC1, aS2, aC2, aS3, aC3);
    }

    ((float4*)(outS + (r0 + 0) * Hd))[lane] = aS0;
    ((float4*)(outS + (r0 + 1) * Hd))[lane] = aS1;
    ((float4*)(outS + (r0 + 2) * Hd))[lane] = aS2;
    ((float4*)(outS + (r0 + 3) * Hd))[lane] = aS3;
    ((ushort4*)(outC + (r0 + 0) * Hd))[lane] = make_ushort4(f2b(aC0.x), f2b(aC0.y), f2b(aC0.z), f2b(aC0.w));
    ((ushort4*)(outC + (r0 + 1) * Hd))[lane] = make_ushort4(f2b(aC1.x), f2b(aC1.y), f2b(aC1.z), f2b(aC1.w));
    ((ushort4*)(outC + (r0 + 2) * Hd))[lane] = make_ushort4(f2b(aC2.x), f2b(aC2.y), f2b(aC2.z), f2b(aC2.w));
    ((ushort4*)(outC + (r0 + 3) * Hd))[lane] = make_ushort4(f2b(aC3.x), f2b(aC3.y), f2b(aC3.z), f2b(aC3.w));
}

// ---------------------------------------------------------------------------
// Combined-relation CSR build: hist -> exclusive scan -> fill.
// src' = writes ? wsrc : N_A + csrc  (indexes rows of msgAll).
// After fill, off[p] = END of segment p.
// ---------------------------------------------------------------------------
__global__ void hist_kernel(const int* __restrict__ wdst, const int EW,
                            const int* __restrict__ cdst, const int EC,
                            int* __restrict__ cnt) {
    for (int i = blockIdx.x * blockDim.x + threadIdx.x; i < EW + EC; i += gridDim.x * blockDim.x) {
        const int d = (i < EW) ? wdst[i] : cdst[i - EW];
        atomicAdd(&cnt[d], 1);
    }
}

__global__ void scan1_kernel(int* __restrict__ data, const int n, int* __restrict__ bsum) {
    __shared__ int s[256];
    const int t = threadIdx.x;
    const int base = blockIdx.x * 1024 + t * 4;
    int v0 = (base + 0 < n) ? data[base + 0] : 0;
    int v1 = (base + 1 < n) ? data[base + 1] : 0;
    int v2 = (base + 2 < n) ? data[base + 2] : 0;
    int v3 = (base + 3 < n) ? data[base + 3] : 0;
    const int tsum = v0 + v1 + v2 + v3;
    s[t] = tsum;
    __syncthreads();
    for (int off = 1; off < 256; off <<= 1) {
        int y = (t >= off) ? s[t - off] : 0;
        __syncthreads();
        if (t >= off) s[t] += y;
        __syncthreads();
    }
    const int e = s[t] - tsum;
    if (base + 0 < n) data[base + 0] = e;
    if (base + 1 < n) data[base + 1] = e + v0;
    if (base + 2 < n) data[base + 2] = e + v0 + v1;
    if (base + 3 < n) data[base + 3] = e + v0 + v1 + v2;
    if (t == 255) bsum[blockIdx.x] = s[255];
}

__global__ void scan2_kernel(int* __restrict__ bsum, const int nb) {
    __shared__ int s[256];
    const int t = threadIdx.x;
    const int v = (t < nb) ? bsum[t] : 0;
    s[t] = v;
    __syncthreads();
    for (int off = 1; off < 256; off <<= 1) {
        int y = (t >= off) ? s[t - off] : 0;
        __syncthreads();
        if (t >= off) s[t] += y;
        __syncthreads();
    }
    if (t < nb) bsum[t] = s[t] - v;
}

__global__ void scan3_kernel(int* __restrict__ data, const int n, const int* __restrict__ bsum) {
    const int i = blockIdx.x * blockDim.x + threadIdx.x;
    if (i < n) data[i] += bsum[i >> 10];
}

__global__ void fill_kernel(const int* __restrict__ wsrc, const int* __restrict__ wdst,
                            const float* __restrict__ ww, const int EW,
                            const int* __restrict__ csrc, const int* __restrict__ cdst,
                            const float* __restrict__ cw, const int EC,
                            int* __restrict__ cur, int2* __restrict__ edges) {
    for (int i = blockIdx.x * blockDim.x + threadIdx.x; i < EW + EC; i += gridDim.x * blockDim.x) {
        int d, sp; float w;
        if (i < EW) { d = wdst[i]; sp = wsrc[i]; w = ww[i]; }
        else        { const int j = i - EW; d = cdst[j]; sp = N_A + csrc[j]; w = cw[j]; }
        const int p = atomicAdd(&cur[d], 1);
        edges[p] = make_int2(sp, __float_as_int(w));
    }
}

// ---------------------------------------------------------------------------
// Pull aggregation (single combined relation) from bf16 msgAll, fp32 accum.
// Block stages its 4 dests' contiguous edge window into LDS (kills the
// meta->gather latency chain), then chunk-4 A/B ping-pong per wave.
// ---------------------------------------------------------------------------
struct AgChunk { ushort4 g0, g1, g2, g3; float w0, w1, w2, w3; };

__device__ __forceinline__ void ag_issue(const int2* __restrict__ eq, const int base, const int n,
                                         const unsigned short* __restrict__ msg,
                                         const int lane, AgChunk& C) {
#define AG_ONE(J, GG, WW) { \
    const int idx = base + (J); \
    const int2 ee = eq[min(idx, n - 1)]; \
    WW = (idx < n) ? __int_as_float(ee.y) : 0.f; \
    GG = ((const ushort4*)(msg + (size_t)ee.x * Hd))[lane]; }
    AG_ONE(0, C.g0, C.w0)
    AG_ONE(1, C.g1, C.w1)
    AG_ONE(2, C.g2, C.w2)
    AG_ONE(3, C.g3, C.w3)
#undef AG_ONE
}

__device__ __forceinline__ void ag_acc(const AgChunk& C, float4& acc) {
#define AG_A(GG, WW) { \
    acc.x = fmaf(WW, b2f(GG.x), acc.x); acc.y = fmaf(WW, b2f(GG.y), acc.y); \
    acc.z = fmaf(WW, b2f(GG.z), acc.z); acc.w = fmaf(WW, b2f(GG.w), acc.w); }
    AG_A(C.g0, C.w0) AG_A(C.g1, C.w1) AG_A(C.g2, C.w2) AG_A(C.g3, C.w3)
#undef AG_A
}

__global__ void aggregate_kernel(float* __restrict__ io,
                                 const unsigned short* __restrict__ msgAll,
                                 const int* __restrict__ off,
                                 const int2* __restrict__ edges,
                                 const int do_elu) {
    __shared__ int2 eq[1024];
    const int wid  = threadIdx.x >> 6;
    const int lane = threadIdx.x & 63;
    const int p0   = blockIdx.x * 4;
    const int sAll = (p0 == 0) ? 0 : off[p0 - 1];
    const int tot  = off[p0 + 3] - sAll;
    const bool fits = (tot <= 1024);
    if (fits)
        for (int i = threadIdx.x; i < tot; i += 256) eq[i] = edges[sAll + i];
    __syncthreads();

    const int p = p0 + wid;
    const int s = (p == 0) ? 0 : off[p - 1];
    const int e = off[p];
    const int n = e - s;
    float4 acc = ((const float4*)(io + (size_t)p * Hd))[lane];

    if (n > 0) {
        if (fits) {
            const int2* eqw = eq + (s - sAll);
            int nc = (n + 3) >> 2;
            nc += (nc & 1);                       // even, >= 2
            AgChunk CA, CB;
            ag_issue(eqw, 0, n, msgAll, lane, CA);
            int c = 1;
            for (; c + 1 < nc; c += 2) {
                ag_issue(eqw, 4 * c, n, msgAll, lane, CB);
                ag_acc(CA, acc);
                ag_issue(eqw, 4 * (c + 1), n, msgAll, lane, CA);
                ag_acc(CB, acc);
            }
            ag_issue(eqw, 4 * (nc - 1), n, msgAll, lane, CB);
            ag_acc(CA, acc);
            ag_acc(CB, acc);
        } else {
            for (int i = s; i < e; ++i) {          // impossible-degree fallback
                const int2 ee = edges[i];
                const ushort4 g = ((const ushort4*)(msgAll + (size_t)ee.x * Hd))[lane];
                const float w = __int_as_float(ee.y);
                acc.x = fmaf(w, b2f(g.x), acc.x); acc.y = fmaf(w, b2f(g.y), acc.y);
                acc.z = fmaf(w, b2f(g.z), acc.z); acc.w = fmaf(w, b2f(g.w), acc.w);
            }
        }
    }
    if (do_elu) {
        acc.x = acc.x > 0.f ? acc.x : expm1f(acc.x);
        acc.y = acc.y > 0.f ? acc.y : expm1f(acc.y);
        acc.z = acc.z > 0.f ? acc.z : expm1f(acc.z);
        acc.w = acc.w > 0.f ? acc.w : expm1f(acc.w);
    }
    ((float4*)(io + (size_t)p * Hd))[lane] = acc;
}

extern "C" void kernel_launch(void* const* d_in, const int* in_sizes, int n_in,
                              void* d_out, int out_size, void* d_ws, size_t ws_size,
                              hipStream_t stream) {
    const float* pf    = (const float*)d_in[0];
    const float* ae    = (const float*)d_in[1];
    const int*   wsrc  = (const int*)d_in[2];
    const int*   wdst  = (const int*)d_in[3];
    const float* ww    = (const float*)d_in[4];
    const int*   csrc  = (const int*)d_in[5];
    const int*   cdst  = (const int*)d_in[6];
    const float* cw    = (const float*)d_in[7];
    const float* W1sp  = (const float*)d_in[8];
    const float* b1sp  = (const float*)d_in[9];
    const float* W1sa  = (const float*)d_in[10];
    const float* b1sa  = (const float*)d_in[11];
    const float* W1rw  = (const float*)d_in[12];
    const float* b1rw  = (const float*)d_in[13];
    const float* W1rc  = (const float*)d_in[14];
    const float* b1rc  = (const float*)d_in[15];
    const float* W2sp  = (const float*)d_in[16];
    const float* b2sp  = (const float*)d_in[17];
    const float* W2sa  = (const float*)d_in[18];
    const float* b2sa  = (const float*)d_in[19];
    const float* W2rw  = (const float*)d_in[20];
    const float* b2rw  = (const float*)d_in[21];
    const float* W2rc  = (const float*)d_in[22];
    const float* b2rc  = (const float*)d_in[23];

    const int E_W = in_sizes[2];
    const int E_C = in_sizes[5];

    float* outP = (float*)d_out;                        // [N_P, 256]
    float* outA = outP + (size_t)N_P * Hd;              // [N_A, 256]

    // Workspace layout:
    // xa1 f32[N_A*256] | msgAll u16[(N_A+N_P)*256] | off[N_P] | edges int2[E] |
    // bsum[256] | bc1 bcA2 bcP2 f32[512] | w1h w1l | wA2h wA2l wP2h wP2l | wcb
    float*          xa1    = (float*)d_ws;
    unsigned short* msgAll = (unsigned short*)(xa1 + (size_t)N_A * Hd);
    unsigned short* msgP   = msgAll + (size_t)N_A * Hd;          // paper-cites msgs
    int*            off    = (int*)(msgAll + (size_t)(N_A + N_P) * Hd);
    int2*           edges  = (int2*)(off + N_P);
    int*            bsum   = (int*)(edges + (E_W + E_C));
    float*          bc1    = (float*)(bsum + 256);
    float*          bcA2   = bc1 + 512;
    float*          bcP2   = bcA2 + 512;
    unsigned short* w1h    = (unsigned short*)(bcP2 + 512);
    unsigned short* w1l    = w1h  + (size_t)128 * 512;
    unsigned short* wA2h   = w1l  + (size_t)128 * 512;
    unsigned short* wA2l   = wA2h + (size_t)256 * 512;
    unsigned short* wP2h   = wA2l + (size_t)256 * 512;
    unsigned short* wP2l   = wP2h + (size_t)256 * 512;
    unsigned short* wcb    = wP2l + (size_t)256 * 512;

    const dim3 blk(256);
    const int  nb = (N_P + 1023) / 1024;      // 98

    // ---------------- prep ----------------
    prep_kernel<<<920, 64, 0, stream>>>(W1sa, W1rw, W2sa, W2rw, W2rc, W2sp, W1rc,
                                        b1sa, b1rw, b2sa, b2rw, b2rc, b2sp,
                                        w1h, w1l, wA2h, wA2l, wP2h, wP2l, wcb,
                                        bc1, bcA2, bcP2);

    // ---------------- combined CSR ----------------
    hipMemsetAsync(off, 0, (size_t)N_P * sizeof(int), stream);
    hist_kernel<<<1024, blk, 0, stream>>>(wdst, E_W, cdst, E_C, off);
    scan1_kernel<<<nb, blk, 0, stream>>>(off, N_P, bsum);
    scan2_kernel<<<1,  blk, 0, stream>>>(bsum, nb);
    scan3_kernel<<<(N_P + 255) / 256, blk, 0, stream>>>(off, N_P, bsum);
    fill_kernel<<<1024, blk, 0, stream>>>(wsrc, wdst, ww, E_W, csrc, cdst, cw, E_C,
                                          off, edges);

    // ---------------- Layer 1 ----------------
    sparse_dual_kernel<<<N_P / 16, blk, 0, stream>>>(pf, W1sp, b1sp, wcb, b1rc,
                                                     outP, msgP);
    mfma_dual_kernel<<<N_A / 32, blk, 128 * 128, stream>>>(ae, 128, w1h, w1l, bc1,
                                                           xa1, msgAll, 1, 0, 0, 1);
    aggregate_kernel<<<N_P / 4, blk, 0, stream>>>(outP, msgAll, off, edges, 1);

    // ---------------- Layer 2 ----------------
    mfma_dual_kernel<<<N_A / 32, blk, 128 * 256, stream>>>(xa1, 256, wA2h, wA2l, bcA2,
                                                           outA, msgAll, 0, 0, 0, 1);
    mfma_dual_kernel<<<N_P / 32, blk, 128 * 256, stream>>>(outP, 256, wP2h, wP2l, bcP2,
                                                           msgP, outP, 0, 0, 1, 0);
    aggregate_kernel<<<N_P / 4, blk, 0, stream>>>(outP, msgAll, off, edges, 0);
}

// Round 7
// 528.249 us; speedup vs baseline: 1.4728x; 1.4728x over previous
//
#include <hip/hip_runtime.h>
#include <cstdint>
#include <cstddef>

constexpr int Hd  = 256;
constexpr int N_P = 100000;
constexpr int N_A = 20000;
constexpr int F_P = 512;
constexpr int D_A = 128;

typedef short bf16x8 __attribute__((ext_vector_type(8)));
typedef float f32x4  __attribute__((ext_vector_type(4)));

// fp32 -> bf16 round-to-nearest-even
__device__ __forceinline__ unsigned short f2b(float x) {
    unsigned u = __float_as_uint(x);
    u += 0x7fffu + ((u >> 16) & 1u);
    return (unsigned short)(u >> 16);
}
__device__ __forceinline__ float b2f(unsigned short h) {
    return __uint_as_float((unsigned)h << 16);
}

// split fp32 into bf16 hi + bf16 lo (truncation; combined error ~2^-16 rel)
__device__ __forceinline__ void bsplit(float x, unsigned short& hi, unsigned short& lo) {
    const unsigned u = __float_as_uint(x);
    hi = (unsigned short)(u >> 16);
    const float r = x - __uint_as_float(u & 0xffff0000u);
    lo = (unsigned short)(__float_as_uint(r) >> 16);
}

// ---------------------------------------------------------------------------
// prep: pack 3 MFMA W-pairs (bf16 hi/lo fragment layout), W1rc as bf16
// row-major (for sparse kernel), and 3 bias concats. One launch, 920 blocks.
// ---------------------------------------------------------------------------
__global__ void prep_kernel(const float* __restrict__ W1sa, const float* __restrict__ W1rw,
                            const float* __restrict__ W2sa, const float* __restrict__ W2rw,
                            const float* __restrict__ W2rc, const float* __restrict__ W2sp,
                            const float* __restrict__ W1rc,
                            const float* __restrict__ b1sa, const float* __restrict__ b1rw,
                            const float* __restrict__ b2sa, const float* __restrict__ b2rw,
                            const float* __restrict__ b2rc, const float* __restrict__ b2sp,
                            unsigned short* __restrict__ w1h,  unsigned short* __restrict__ w1l,
                            unsigned short* __restrict__ wA2h, unsigned short* __restrict__ wA2l,
                            unsigned short* __restrict__ wP2h, unsigned short* __restrict__ wP2l,
                            unsigned short* __restrict__ wcb,
                            float* __restrict__ bc1, float* __restrict__ bcA2,
                            float* __restrict__ bcP2) {
    const int b = blockIdx.x;
    if (b < 640) {
        const float *Wa, *Wb; unsigned short *wh, *wl; int rel;
        if (b < 128)      { Wa = W1sa; Wb = W1rw; wh = w1h;  wl = w1l;  rel = b; }
        else if (b < 384) { Wa = W2sa; Wb = W2rw; wh = wA2h; wl = wA2l; rel = b - 128; }
        else              { Wa = W2rc; Wb = W2sp; wh = wP2h; wl = wP2l; rel = b - 384; }
        const int ks  = rel >> 5;
        const int nfg = rel & 31;
        const int l   = threadIdx.x;
        const float* W = (nfg < 16) ? Wa : Wb;
        const int col  = (nfg & 15) * 16 + (l & 15);
        const size_t base = ((size_t)rel * 64 + l) * 8;
        #pragma unroll
        for (int j = 0; j < 8; ++j) {
            const int k = ks * 32 + ((l >> 4) * 8) + j;
            unsigned short h, lw;
            bsplit(W[(size_t)k * Hd + col], h, lw);
            wh[base + j] = h;
            wl[base + j] = lw;
        }
    } else if (b < 896) {
        const int i0 = (b - 640) * 512 + threadIdx.x * 8;
        #pragma unroll
        for (int j = 0; j < 8; ++j) wcb[i0 + j] = f2b(W1rc[i0 + j]);
    } else {
        const int t     = (b - 896) * 64 + threadIdx.x;   // 0..1535
        const int which = t >> 9;
        const int idx   = t & 511;
        const float* src; float* dst;
        if (which == 0)      { src = (idx < 256) ? b1sa : b1rw; dst = bc1; }
        else if (which == 1) { src = (idx < 256) ? b2sa : b2rw; dst = bcA2; }
        else                 { src = (idx < 256) ? b2rc : b2sp; dst = bcP2; }
        dst[idx] = src[idx & 255];
    }
}

// ---------------------------------------------------------------------------
// Dual-output MFMA GEMM, ABF=0: fp32 A, split-bf16 3-product;
// ABF=1: bf16 A (exact), 2-product. Outputs independently fp32 or bf16.
// A fully staged to LDS before __syncthreads(), stores after (in-place safe).
// ---------------------------------------------------------------------------
template<int ABF>
__global__ void mfma_dual_kernel(const void* __restrict__ Av, const int K,
                                 const unsigned short* __restrict__ whi,
                                 const unsigned short* __restrict__ wlo,
                                 const float* __restrict__ bcat,
                                 void* __restrict__ Oa, void* __restrict__ Ob,
                                 const int actA, const int actB,
                                 const int bfA, const int bfB) {
    extern __shared__ char smem[];
    char* sh = smem;
    char* sl = smem + 32 * K * 2;                // unused when ABF=1
    const int  tid = threadIdx.x;
    const int  wid = tid >> 6;
    const int  l   = tid & 63;
    const long m0  = (long)blockIdx.x * 32;
    const int  rowStride = 2 * K;

    const int kq4 = K >> 2;
    if constexpr (ABF) {
        const unsigned short* A = (const unsigned short*)Av;
        for (int i = tid; i < 32 * kq4; i += 256) {
            const int row = i / kq4;
            const int kq  = i - row * kq4;
            const ushort4 v = *(const ushort4*)(A + (m0 + row) * K + kq * 4);
            const int ofs = row * rowStride + ((kq * 8) ^ ((row & 7) << 4));
            *(ushort4*)(sh + ofs) = v;
        }
    } else {
        const float* A = (const float*)Av;
        for (int i = tid; i < 32 * kq4; i += 256) {
            const int row = i / kq4;
            const int kq  = i - row * kq4;
            const float4 v = *(const float4*)(A + (m0 + row) * K + kq * 4);
            unsigned short h0, h1, h2, h3, l0, l1, l2, l3;
            bsplit(v.x, h0, l0); bsplit(v.y, h1, l1);
            bsplit(v.z, h2, l2); bsplit(v.w, h3, l3);
            const int ofs = row * rowStride + ((kq * 8) ^ ((row & 7) << 4));
            *(ushort4*)(sh + ofs) = make_ushort4(h0, h1, h2, h3);
            *(ushort4*)(sl + ofs) = make_ushort4(l0, l1, l2, l3);
        }
    }
    __syncthreads();

    f32x4 acc[2][8];
    #pragma unroll
    for (int nf = 0; nf < 8; ++nf) {
        const float b = bcat[wid * 128 + nf * 16 + (l & 15)];
        acc[0][nf] = (f32x4){b, b, b, b};
        acc[1][nf] = (f32x4){b, b, b, b};
    }

    const int kb  = (l >> 4) * 16;
    const int r0  = l & 15;
    const int r1  = 16 + r0;
    const int sw  = (l & 7) << 4;
    const int ro0 = r0 * rowStride;
    const int ro1 = r1 * rowStride;
    for (int ks = 0; ks < (K >> 5); ++ks) {
        const int bk = (ks * 64 + kb) ^ sw;
        const bf16x8 ah0 = *(const bf16x8*)(sh + ro0 + bk);
        const bf16x8 ah1 = *(const bf16x8*)(sh + ro1 + bk);
        bf16x8 al0, al1;
        if constexpr (!ABF) {
            al0 = *(const bf16x8*)(sl + ro0 + bk);
            al1 = *(const bf16x8*)(sl + ro1 + bk);
        }
        const size_t wbase = (((size_t)ks * 32 + wid * 8) * 64 + l) * 8;
        #pragma unroll
        for (int nf = 0; nf < 8; ++nf) {
            const bf16x8 bh = *(const bf16x8*)(whi + wbase + (size_t)nf * 512);
            const bf16x8 bl = *(const bf16x8*)(wlo + wbase + (size_t)nf * 512);
            acc[0][nf] = __builtin_amdgcn_mfma_f32_16x16x32_bf16(ah0, bh, acc[0][nf], 0, 0, 0);
            acc[1][nf] = __builtin_amdgcn_mfma_f32_16x16x32_bf16(ah1, bh, acc[1][nf], 0, 0, 0);
            if constexpr (!ABF) {
                acc[0][nf] = __builtin_amdgcn_mfma_f32_16x16x32_bf16(al0, bh, acc[0][nf], 0, 0, 0);
                acc[1][nf] = __builtin_amdgcn_mfma_f32_16x16x32_bf16(al1, bh, acc[1][nf], 0, 0, 0);
            }
            acc[0][nf] = __builtin_amdgcn_mfma_f32_16x16x32_bf16(ah0, bl, acc[0][nf], 0, 0, 0);
            acc[1][nf] = __builtin_amdgcn_mfma_f32_16x16x32_bf16(ah1, bl, acc[1][nf], 0, 0, 0);
        }
    }

    #pragma unroll
    for (int mf = 0; mf < 2; ++mf) {
        #pragma unroll
        for (int nf = 0; nf < 8; ++nf) {
            const int colg = wid * 128 + nf * 16 + (l & 15);
            void* O;
            int col, act, isbf;
            if (colg < 256) { O = Oa; col = colg;       act = actA; isbf = bfA; }
            else            { O = Ob; col = colg - 256; act = actB; isbf = bfB; }
            const long row = m0 + mf * 16 + ((l >> 4) * 4);
            const f32x4 v = acc[mf][nf];
            #pragma unroll
            for (int r = 0; r < 4; ++r) {
                float x = v[r];
                if (act) x = x > 0.f ? x : expm1f(x);
                if (isbf) ((unsigned short*)O)[(row + r) * Hd + col] = f2b(x);
                else      ((float*)O)[(row + r) * Hd + col] = x;
            }
        }
    }
}

// ---------------------------------------------------------------------------
// Sparse dual GEMM over BINARY multi-hot pf (values exactly 0/1). Wave = 4
// rows. Phase 1: ballot-prefix compaction of u16 entries (k | row<<9 |
// pad<<11) into a wave-private LDS queue. Phase 2: chunk-4 ping-pong walk --
// entries readfirstlane'd to SGPRs (wave-uniform), SCALAR branches route
// adds to NAMED accumulators, two named load buffers (16 loads in flight).
// No structs/arrays in the pipeline -> no scratch spill (R6 lesson).
// Both outputs bf16.
// ---------------------------------------------------------------------------
__global__ void __launch_bounds__(256, 2)
sparse_dual_kernel(const float* __restrict__ pf,
                   const float* __restrict__ Ws, const float* __restrict__ bs,
                   const unsigned short* __restrict__ Wc, const float* __restrict__ bc,
                   unsigned short* __restrict__ outS, unsigned short* __restrict__ outC) {
    __shared__ unsigned short q[4][176];
    const int lane = threadIdx.x & 63;
    const int wid  = threadIdx.x >> 6;
    const long r0  = (long)blockIdx.x * 16 + wid * 4;
    unsigned short* wq = q[wid];

    // ---- phase 0: load pf for 4 rows (8 dwordx4 in flight) ----
    const float4* p0 = (const float4*)(pf + (r0 + 0) * F_P);
    const float4* p1 = (const float4*)(pf + (r0 + 1) * F_P);
    const float4* p2 = (const float4*)(pf + (r0 + 2) * F_P);
    const float4* p3 = (const float4*)(pf + (r0 + 3) * F_P);
    const float4 A0 = p0[lane], B0 = p0[64 + lane];
    const float4 A1 = p1[lane], B1 = p1[64 + lane];
    const float4 A2 = p2[lane], B2 = p2[64 + lane];
    const float4 A3 = p3[lane], B3 = p3[64 + lane];

    // ---- phase 1: ballot-prefix compaction into LDS queue ----
    int qn = 0;
#define SP_GRP(VAL, KOFS, ROW) { \
    const bool nz = (VAL) != 0.f; \
    const unsigned long long mk = __ballot(nz); \
    if (nz) { \
        const int within = __builtin_amdgcn_mbcnt_hi((unsigned)(mk >> 32), \
                           __builtin_amdgcn_mbcnt_lo((unsigned)mk, 0)); \
        wq[qn + within] = (unsigned short)(((KOFS) + lane * 4) | ((ROW) << 9)); \
    } \
    qn += (int)__popcll(mk); }
    SP_GRP(A0.x, 0,   0) SP_GRP(A0.y, 1,   0) SP_GRP(A0.z, 2,   0) SP_GRP(A0.w, 3,   0)
    SP_GRP(B0.x, 256, 0) SP_GRP(B0.y, 257, 0) SP_GRP(B0.z, 258, 0) SP_GRP(B0.w, 259, 0)
    SP_GRP(A1.x, 0,   1) SP_GRP(A1.y, 1,   1) SP_GRP(A1.z, 2,   1) SP_GRP(A1.w, 3,   1)
    SP_GRP(B1.x, 256, 1) SP_GRP(B1.y, 257, 1) SP_GRP(B1.z, 258, 1) SP_GRP(B1.w, 259, 1)
    SP_GRP(A2.x, 0,   2) SP_GRP(A2.y, 1,   2) SP_GRP(A2.z, 2,   2) SP_GRP(A2.w, 3,   2)
    SP_GRP(B2.x, 256, 2) SP_GRP(B2.y, 257, 2) SP_GRP(B2.z, 258, 2) SP_GRP(B2.w, 259, 2)
    SP_GRP(A3.x, 0,   3) SP_GRP(A3.y, 1,   3) SP_GRP(A3.z, 2,   3) SP_GRP(A3.w, 3,   3)
    SP_GRP(B3.x, 256, 3) SP_GRP(B3.y, 257, 3) SP_GRP(B3.z, 258, 3) SP_GRP(B3.w, 259, 3)
#undef SP_GRP
    // pad to multiple of 8 (min 8) with pad entries (bit 11 set -> skipped)
    int qnp = (qn + 7) & ~7;
    if (qnp == 0) qnp = 8;
    if (lane < qnp - qn) wq[qn + lane] = 0x0800;
    __syncthreads();

    // ---- phase 2: chunk-4 ping-pong pipelined walk ----
    float4 aS0, aC0;
    { const float4 bsv = ((const float4*)bs)[lane]; aS0 = bsv; }
    { const float4 bcv = ((const float4*)bc)[lane]; aC0 = bcv; }
    float4 aS1 = aS0, aS2 = aS0, aS3 = aS0;
    float4 aC1 = aC0, aC2 = aC0, aC3 = aC0;

#define DEC1(EV, K, R, P) { const int e_ = __builtin_amdgcn_readfirstlane((int)(EV)); \
    K = e_ & 511; R = (e_ >> 9) & 3; P = e_ >> 11; }
#define ISS1(S4, C4, K) { \
    S4 = ((const float4*)(Ws + ((size_t)(K) << 8)))[lane]; \
    C4 = ((const ushort4*)(Wc + ((size_t)(K) << 8)))[lane]; }
#define ACC1(S4, C4, R, P) if (!(P)) { \
    if ((R) == 0)      { aS0.x += S4.x; aS0.y += S4.y; aS0.z += S4.z; aS0.w += S4.w; \
                         aC0.x += b2f(C4.x); aC0.y += b2f(C4.y); aC0.z += b2f(C4.z); aC0.w += b2f(C4.w); } \
    else if ((R) == 1) { aS1.x += S4.x; aS1.y += S4.y; aS1.z += S4.z; aS1.w += S4.w; \
                         aC1.x += b2f(C4.x); aC1.y += b2f(C4.y); aC1.z += b2f(C4.z); aC1.w += b2f(C4.w); } \
    else if ((R) == 2) { aS2.x += S4.x; aS2.y += S4.y; aS2.z += S4.z; aS2.w += S4.w; \
                         aC2.x += b2f(C4.x); aC2.y += b2f(C4.y); aC2.z += b2f(C4.z); aC2.w += b2f(C4.w); } \
    else               { aS3.x += S4.x; aS3.y += S4.y; aS3.z += S4.z; aS3.w += S4.w; \
                         aC3.x += b2f(C4.x); aC3.y += b2f(C4.y); aC3.z += b2f(C4.z); aC3.w += b2f(C4.w); } }

    const int nch = qnp >> 2;                    // even, >= 2
    int kA0, kA1, kA2, kA3, rA0, rA1, rA2, rA3, pA0, pA1, pA2, pA3;
    int kB0, kB1, kB2, kB3, rB0, rB1, rB2, rB3, pB0, pB1, pB2, pB3;
    float4  sA0, sA1, sA2, sA3, sB0, sB1, sB2, sB3;
    ushort4 cA0, cA1, cA2, cA3, cB0, cB1, cB2, cB3;

    ushort4 qv = *(const ushort4*)(wq + 0);
    DEC1(qv.x, kA0, rA0, pA0) DEC1(qv.y, kA1, rA1, pA1)
    DEC1(qv.z, kA2, rA2, pA2) DEC1(qv.w, kA3, rA3, pA3)
    ISS1(sA0, cA0, kA0) ISS1(sA1, cA1, kA1) ISS1(sA2, cA2, kA2) ISS1(sA3, cA3, kA3)
    qv = *(const ushort4*)(wq + 4);
    DEC1(qv.x, kB0, rB0, pB0) DEC1(qv.y, kB1, rB1, pB1)
    DEC1(qv.z, kB2, rB2, pB2) DEC1(qv.w, kB3, rB3, pB3)
    ISS1(sB0, cB0, kB0) ISS1(sB1, cB1, kB1) ISS1(sB2, cB2, kB2) ISS1(sB3, cB3, kB3)

    for (int c = 0; c + 2 < nch; c += 2) {
        qv = *(const ushort4*)(wq + 4 * (c + 2));
        ACC1(sA0, cA0, rA0, pA0) ACC1(sA1, cA1, rA1, pA1)
        ACC1(sA2, cA2, rA2, pA2) ACC1(sA3, cA3, rA3, pA3)
        DEC1(qv.x, kA0, rA0, pA0) DEC1(qv.y, kA1, rA1, pA1)
        DEC1(qv.z, kA2, rA2, pA2) DEC1(qv.w, kA3, rA3, pA3)
        ISS1(sA0, cA0, kA0) ISS1(sA1, cA1, kA1) ISS1(sA2, cA2, kA2) ISS1(sA3, cA3, kA3)
        qv = *(const ushort4*)(wq + 4 * (c + 3));
        ACC1(sB0, cB0, rB0, pB0) ACC1(sB1, cB1, rB1, pB1)
        ACC1(sB2, cB2, rB2, pB2) ACC1(sB3, cB3, rB3, pB3)
        DEC1(qv.x, kB0, rB0, pB0) DEC1(qv.y, kB1, rB1, pB1)
        DEC1(qv.z, kB2, rB2, pB2) DEC1(qv.w, kB3, rB3, pB3)
        ISS1(sB0, cB0, kB0) ISS1(sB1, cB1, kB1) ISS1(sB2, cB2, kB2) ISS1(sB3, cB3, kB3)
    }
    ACC1(sA0, cA0, rA0, pA0) ACC1(sA1, cA1, rA1, pA1)
    ACC1(sA2, cA2, rA2, pA2) ACC1(sA3, cA3, rA3, pA3)
    ACC1(sB0, cB0, rB0, pB0) ACC1(sB1, cB1, rB1, pB1)
    ACC1(sB2, cB2, rB2, pB2) ACC1(sB3, cB3, rB3, pB3)
#undef DEC1
#undef ISS1
#undef ACC1

    ((ushort4*)(outS + (r0 + 0) * Hd))[lane] = make_ushort4(f2b(aS0.x), f2b(aS0.y), f2b(aS0.z), f2b(aS0.w));
    ((ushort4*)(outS + (r0 + 1) * Hd))[lane] = make_ushort4(f2b(aS1.x), f2b(aS1.y), f2b(aS1.z), f2b(aS1.w));
    ((ushort4*)(outS + (r0 + 2) * Hd))[lane] = make_ushort4(f2b(aS2.x), f2b(aS2.y), f2b(aS2.z), f2b(aS2.w));
    ((ushort4*)(outS + (r0 + 3) * Hd))[lane] = make_ushort4(f2b(aS3.x), f2b(aS3.y), f2b(aS3.z), f2b(aS3.w));
    ((ushort4*)(outC + (r0 + 0) * Hd))[lane] = make_ushort4(f2b(aC0.x), f2b(aC0.y), f2b(aC0.z), f2b(aC0.w));
    ((ushort4*)(outC + (r0 + 1) * Hd))[lane] = make_ushort4(f2b(aC1.x), f2b(aC1.y), f2b(aC1.z), f2b(aC1.w));
    ((ushort4*)(outC + (r0 + 2) * Hd))[lane] = make_ushort4(f2b(aC2.x), f2b(aC2.y), f2b(aC2.z), f2b(aC2.w));
    ((ushort4*)(outC + (r0 + 3) * Hd))[lane] = make_ushort4(f2b(aC3.x), f2b(aC3.y), f2b(aC3.z), f2b(aC3.w));
}

// ---------------------------------------------------------------------------
// Combined-relation CSR build. src' = writes ? wsrc : N_A + csrc.
// After fill, off[p] = END of segment p.
// ---------------------------------------------------------------------------
__global__ void hist_kernel(const int* __restrict__ wdst, const int EW,
                            const int* __restrict__ cdst, const int EC,
                            int* __restrict__ cnt) {
    for (int i = blockIdx.x * blockDim.x + threadIdx.x; i < EW + EC; i += gridDim.x * blockDim.x) {
        const int d = (i < EW) ? wdst[i] : cdst[i - EW];
        atomicAdd(&cnt[d], 1);
    }
}

__global__ void scan1_kernel(int* __restrict__ data, const int n, int* __restrict__ bsum) {
    __shared__ int s[256];
    const int t = threadIdx.x;
    const int base = blockIdx.x * 1024 + t * 4;
    int v0 = (base + 0 < n) ? data[base + 0] : 0;
    int v1 = (base + 1 < n) ? data[base + 1] : 0;
    int v2 = (base + 2 < n) ? data[base + 2] : 0;
    int v3 = (base + 3 < n) ? data[base + 3] : 0;
    const int tsum = v0 + v1 + v2 + v3;
    s[t] = tsum;
    __syncthreads();
    for (int off = 1; off < 256; off <<= 1) {
        int y = (t >= off) ? s[t - off] : 0;
        __syncthreads();
        if (t >= off) s[t] += y;
        __syncthreads();
    }
    const int e = s[t] - tsum;
    if (base + 0 < n) data[base + 0] = e;
    if (base + 1 < n) data[base + 1] = e + v0;
    if (base + 2 < n) data[base + 2] = e + v0 + v1;
    if (base + 3 < n) data[base + 3] = e + v0 + v1 + v2;
    if (t == 255) bsum[blockIdx.x] = s[255];
}

__global__ void scan2_kernel(int* __restrict__ bsum, const int nb) {
    __shared__ int s[256];
    const int t = threadIdx.x;
    const int v = (t < nb) ? bsum[t] : 0;
    s[t] = v;
    __syncthreads();
    for (int off = 1; off < 256; off <<= 1) {
        int y = (t >= off) ? s[t - off] : 0;
        __syncthreads();
        if (t >= off) s[t] += y;
        __syncthreads();
    }
    if (t < nb) bsum[t] = s[t] - v;
}

__global__ void scan3_kernel(int* __restrict__ data, const int n, const int* __restrict__ bsum) {
    const int i = blockIdx.x * blockDim.x + threadIdx.x;
    if (i < n) data[i] += bsum[i >> 10];
}

__global__ void fill_kernel(const int* __restrict__ wsrc, const int* __restrict__ wdst,
                            const float* __restrict__ ww, const int EW,
                            const int* __restrict__ csrc, const int* __restrict__ cdst,
                            const float* __restrict__ cw, const int EC,
                            int* __restrict__ cur, int2* __restrict__ edges) {
    for (int i = blockIdx.x * blockDim.x + threadIdx.x; i < EW + EC; i += gridDim.x * blockDim.x) {
        int d, sp; float w;
        if (i < EW) { d = wdst[i]; sp = wsrc[i]; w = ww[i]; }
        else        { const int j = i - EW; d = cdst[j]; sp = N_A + csrc[j]; w = cw[j]; }
        const int p = atomicAdd(&cur[d], 1);
        edges[p] = make_int2(sp, __float_as_int(w));
    }
}

// ---------------------------------------------------------------------------
// Pull aggregation (combined relation) from bf16 msgAll, fp32 accumulate.
// IOBF: io buffer is bf16 (layer 1) or fp32 (layer 2). Block stages its 4
// dests' edge window in LDS; chunk-4 A/B ping-pong per wave.
// ---------------------------------------------------------------------------
struct AgChunk { ushort4 g0, g1, g2, g3; float w0, w1, w2, w3; };

__device__ __forceinline__ void ag_issue(const int2* __restrict__ eq, const int base, const int n,
                                         const unsigned short* __restrict__ msg,
                                         const int lane, AgChunk& C) {
#define AG_ONE(J, GG, WW) { \
    const int idx = base + (J); \
    const int2 ee = eq[min(idx, n - 1)]; \
    WW = (idx < n) ? __int_as_float(ee.y) : 0.f; \
    GG = ((const ushort4*)(msg + (size_t)ee.x * Hd))[lane]; }
    AG_ONE(0, C.g0, C.w0)
    AG_ONE(1, C.g1, C.w1)
    AG_ONE(2, C.g2, C.w2)
    AG_ONE(3, C.g3, C.w3)
#undef AG_ONE
}

__device__ __forceinline__ void ag_acc(const AgChunk& C, float4& acc) {
#define AG_A(GG, WW) { \
    acc.x = fmaf(WW, b2f(GG.x), acc.x); acc.y = fmaf(WW, b2f(GG.y), acc.y); \
    acc.z = fmaf(WW, b2f(GG.z), acc.z); acc.w = fmaf(WW, b2f(GG.w), acc.w); }
    AG_A(C.g0, C.w0) AG_A(C.g1, C.w1) AG_A(C.g2, C.w2) AG_A(C.g3, C.w3)
#undef AG_A
}

template<int IOBF>
__global__ void aggregate_kernel(void* __restrict__ iov,
                                 const unsigned short* __restrict__ msgAll,
                                 const int* __restrict__ off,
                                 const int2* __restrict__ edges,
                                 const int do_elu) {
    __shared__ int2 eq[1024];
    const int wid  = threadIdx.x >> 6;
    const int lane = threadIdx.x & 63;
    const int p0   = blockIdx.x * 4;
    const int sAll = (p0 == 0) ? 0 : off[p0 - 1];
    const int tot  = off[p0 + 3] - sAll;
    const bool fits = (tot <= 1024);
    if (fits)
        for (int i = threadIdx.x; i < tot; i += 256) eq[i] = edges[sAll + i];
    __syncthreads();

    const int p = p0 + wid;
    const int s = (p == 0) ? 0 : off[p - 1];
    const int e = off[p];
    const int n = e - s;

    float4 acc;
    if constexpr (IOBF) {
        const ushort4 t = ((const ushort4*)((const unsigned short*)iov + (size_t)p * Hd))[lane];
        acc = make_float4(b2f(t.x), b2f(t.y), b2f(t.z), b2f(t.w));
    } else {
        acc = ((const float4*)((const float*)iov + (size_t)p * Hd))[lane];
    }

    if (n > 0) {
        if (fits) {
            const int2* eqw = eq + (s - sAll);
            int nc = (n + 3) >> 2;
            nc += (nc & 1);                       // even, >= 2
            AgChunk CA, CB;
            ag_issue(eqw, 0, n, msgAll, lane, CA);
            int c = 1;
            for (; c + 1 < nc; c += 2) {
                ag_issue(eqw, 4 * c, n, msgAll, lane, CB);
                ag_acc(CA, acc);
                ag_issue(eqw, 4 * (c + 1), n, msgAll, lane, CA);
                ag_acc(CB, acc);
            }
            ag_issue(eqw, 4 * (nc - 1), n, msgAll, lane, CB);
            ag_acc(CA, acc);
            ag_acc(CB, acc);
        } else {
            for (int i = s; i < e; ++i) {
                const int2 ee = edges[i];
                const ushort4 g = ((const ushort4*)(msgAll + (size_t)ee.x * Hd))[lane];
                const float w = __int_as_float(ee.y);
                acc.x = fmaf(w, b2f(g.x), acc.x); acc.y = fmaf(w, b2f(g.y), acc.y);
                acc.z = fmaf(w, b2f(g.z), acc.z); acc.w = fmaf(w, b2f(g.w), acc.w);
            }
        }
    }
    if (do_elu) {
        acc.x = acc.x > 0.f ? acc.x : expm1f(acc.x);
        acc.y = acc.y > 0.f ? acc.y : expm1f(acc.y);
        acc.z = acc.z > 0.f ? acc.z : expm1f(acc.z);
        acc.w = acc.w > 0.f ? acc.w : expm1f(acc.w);
    }
    if constexpr (IOBF) {
        ((ushort4*)((unsigned short*)iov + (size_t)p * Hd))[lane] =
            make_ushort4(f2b(acc.x), f2b(acc.y), f2b(acc.z), f2b(acc.w));
    } else {
        ((float4*)((float*)iov + (size_t)p * Hd))[lane] = acc;
    }
}

extern "C" void kernel_launch(void* const* d_in, const int* in_sizes, int n_in,
                              void* d_out, int out_size, void* d_ws, size_t ws_size,
                              hipStream_t stream) {
    const float* pf    = (const float*)d_in[0];
    const float* ae    = (const float*)d_in[1];
    const int*   wsrc  = (const int*)d_in[2];
    const int*   wdst  = (const int*)d_in[3];
    const float* ww    = (const float*)d_in[4];
    const int*   csrc  = (const int*)d_in[5];
    const int*   cdst  = (const int*)d_in[6];
    const float* cw    = (const float*)d_in[7];
    const float* W1sp  = (const float*)d_in[8];
    const float* b1sp  = (const float*)d_in[9];
    const float* W1sa  = (const float*)d_in[10];
    const float* b1sa  = (const float*)d_in[11];
    const float* W1rw  = (const float*)d_in[12];
    const float* b1rw  = (const float*)d_in[13];
    const float* W1rc  = (const float*)d_in[14];
    const float* b1rc  = (const float*)d_in[15];
    const float* W2sp  = (const float*)d_in[16];
    const float* b2sp  = (const float*)d_in[17];
    const float* W2sa  = (const float*)d_in[18];
    const float* b2sa  = (const float*)d_in[19];
    const float* W2rw  = (const float*)d_in[20];
    const float* b2rw  = (const float*)d_in[21];
    const float* W2rc  = (const float*)d_in[22];
    const float* b2rc  = (const float*)d_in[23];

    const int E_W = in_sizes[2];
    const int E_C = in_sizes[5];

    float* outP = (float*)d_out;                        // [N_P, 256] fp32
    float* outA = outP + (size_t)N_P * Hd;              // [N_A, 256] fp32

    // Workspace layout:
    // xa1 f32[N_A*256] | xp1b u16[N_P*256] | msgAll u16[(N_A+N_P)*256] |
    // off[N_P] | edges int2[E] | bsum[256] | bc1 bcA2 bcP2 f32[512] |
    // w1h w1l | wA2h wA2l wP2h wP2l | wcb
    float*          xa1    = (float*)d_ws;
    unsigned short* xp1b   = (unsigned short*)(xa1 + (size_t)N_A * Hd);
    unsigned short* msgAll = xp1b + (size_t)N_P * Hd;
    unsigned short* msgP   = msgAll + (size_t)N_A * Hd;
    int*            off    = (int*)(msgAll + (size_t)(N_A + N_P) * Hd);
    int2*           edges  = (int2*)(off + N_P);
    int*            bsum   = (int*)(edges + (E_W + E_C));
    float*          bc1    = (float*)(bsum + 256);
    float*          bcA2   = bc1 + 512;
    float*          bcP2   = bcA2 + 512;
    unsigned short* w1h    = (unsigned short*)(bcP2 + 512);
    unsigned short* w1l    = w1h  + (size_t)128 * 512;
    unsigned short* wA2h   = w1l  + (size_t)128 * 512;
    unsigned short* wA2l   = wA2h + (size_t)256 * 512;
    unsigned short* wP2h   = wA2l + (size_t)256 * 512;
    unsigned short* wP2l   = wP2h + (size_t)256 * 512;
    unsigned short* wcb    = wP2l + (size_t)256 * 512;

    const dim3 blk(256);
    const int  nb = (N_P + 1023) / 1024;      // 98

    // ---------------- prep ----------------
    prep_kernel<<<920, 64, 0, stream>>>(W1sa, W1rw, W2sa, W2rw, W2rc, W2sp, W1rc,
                                        b1sa, b1rw, b2sa, b2rw, b2rc, b2sp,
                                        w1h, w1l, wA2h, wA2l, wP2h, wP2l, wcb,
                                        bc1, bcA2, bcP2);

    // ---------------- combined CSR ----------------
    hipMemsetAsync(off, 0, (size_t)N_P * sizeof(int), stream);
    hist_kernel<<<1024, blk, 0, stream>>>(wdst, E_W, cdst, E_C, off);
    scan1_kernel<<<nb, blk, 0, stream>>>(off, N_P, bsum);
    scan2_kernel<<<1,  blk, 0, stream>>>(bsum, nb);
    scan3_kernel<<<(N_P + 255) / 256, blk, 0, stream>>>(off, N_P, bsum);
    fill_kernel<<<1024, blk, 0, stream>>>(wsrc, wdst, ww, E_W, csrc, cdst, cw, E_C,
                                          off, edges);

    // ---------------- Layer 1 ----------------
    // paper self (bf16 xp1b) + cites msg (bf16 msgP), one pass over pf
    sparse_dual_kernel<<<N_P / 16, blk, 0, stream>>>(pf, W1sp, b1sp, wcb, b1rc,
                                                     xp1b, msgP);
    // author self (ELU, fp32 xa1) + writes msg (bf16 into msgAll)
    mfma_dual_kernel<0><<<N_A / 32, blk, 32 * 128 * 4, stream>>>(ae, 128, w1h, w1l, bc1,
                                                                 xa1, msgAll, 1, 0, 0, 1);
    aggregate_kernel<1><<<N_P / 4, blk, 0, stream>>>(xp1b, msgAll, off, edges, 1);

    // ---------------- Layer 2 ----------------
    mfma_dual_kernel<0><<<N_A / 32, blk, 32 * 256 * 4, stream>>>(xa1, 256, wA2h, wA2l, bcA2,
                                                                 outA, msgAll, 0, 0, 0, 1);
    // paper: A = xp1b (bf16, 2-product) -> cites msg (bf16) + self (fp32 outP)
    mfma_dual_kernel<1><<<N_P / 32, blk, 32 * 256 * 2, stream>>>(xp1b, 256, wP2h, wP2l, bcP2,
                                                                 msgP, outP, 0, 0, 1, 0);
    aggregate_kernel<0><<<N_P / 4, blk, 0, stream>>>(outP, msgAll, off, edges, 0);
}